// Round 3
// baseline (1010.745 us; speedup 1.0000x reference)
//
#include <hip/hip_runtime.h>

#define D_FEAT 64
#define NN 100000
#define BROWS 64                       // rows per bucket
#define NBUCK ((NN + BROWS - 1) / BROWS)   // 1563

// ---------------- Phase A: coarse histogram (LDS-privatized) ----------------
__global__ void hist_bucket(const int* __restrict__ rows, int* __restrict__ counts, int E) {
    __shared__ int h[NBUCK];
    for (int i = threadIdx.x; i < NBUCK; i += blockDim.x) h[i] = 0;
    __syncthreads();
    int i = blockIdx.x * blockDim.x + threadIdx.x;
    int stride = gridDim.x * blockDim.x;
    for (; i < E; i += stride) atomicAdd(&h[rows[i] >> 6], 1);
    __syncthreads();
    for (int b = threadIdx.x; b < NBUCK; b += blockDim.x) {
        int v = h[b];
        if (v) atomicAdd(&counts[b], v);
    }
}

// ---------------- Phase B: exclusive scan over NBUCK counts (one block) ----------------
__global__ void scan_small(const int* __restrict__ counts, int* __restrict__ offsets, int E) {
    __shared__ int tsum[256];
    const int per = (NBUCK + 255) / 256;   // 7
    int t = threadIdx.x;
    int base = t * per;
    int loc[8];
    int s = 0;
    for (int k = 0; k < per; k++) {
        int idx = base + k;
        int v = (idx < NBUCK) ? counts[idx] : 0;
        loc[k] = s; s += v;
    }
    tsum[t] = s; __syncthreads();
    for (int off = 1; off < 256; off <<= 1) {
        int x = (t >= off) ? tsum[t - off] : 0;
        __syncthreads();
        tsum[t] += x;
        __syncthreads();
    }
    int excl = (t > 0) ? tsum[t - 1] : 0;
    for (int k = 0; k < per; k++) {
        int idx = base + k;
        if (idx < NBUCK) offsets[idx] = excl + loc[k];
    }
    if (t == 0) offsets[NBUCK] = E;
}

// ---------------- Phase C: scatter edges into bucket regions ----------------
// Payload packs (col | rloc<<17, val): col < 2^17, rloc = row % 64 < 2^6.
__global__ void cscatter_kernel(const int* __restrict__ rows, const int* __restrict__ cols,
                                const float* __restrict__ vals,
                                const int* __restrict__ offsets, int* __restrict__ cursors,
                                int2* __restrict__ sedges, int E) {
    int i = blockIdx.x * blockDim.x + threadIdx.x;
    int stride = gridDim.x * blockDim.x;
    for (; i < E; i += stride) {
        int r = rows[i];
        int bkt = r >> 6;
        int pos = offsets[bkt] + atomicAdd(&cursors[bkt], 1);
        sedges[pos] = make_int2(cols[i] | ((r & 63) << 17), __float_as_int(vals[i]));
    }
}

// ---------------- Phase D: bucket SpMM with LDS accumulator ----------------
// One block per bucket. LDS acc[64 rows][64 feats] = 16 KB. lane = feature.
__global__ void __launch_bounds__(256) bucket_spmm(const int* __restrict__ offsets,
                                                   const int2* __restrict__ sedges,
                                                   const float* __restrict__ embeds,
                                                   float* __restrict__ out) {
    __shared__ float acc[BROWS * D_FEAT];
    float4* acc4 = (float4*)acc;
    for (int i = threadIdx.x; i < BROWS * D_FEAT / 4; i += 256)
        acc4[i] = make_float4(0.f, 0.f, 0.f, 0.f);
    __syncthreads();

    int b = blockIdx.x;
    int s = offsets[b], e = offsets[b + 1];
    int lane = threadIdx.x & 63;
    int w = threadIdx.x >> 6;

    for (int i = s + w; i < e; i += 4) {
        int2 se = sedges[i];
        int col  = se.x & 0x1FFFF;
        int rloc = (se.x >> 17) & 63;
        float v  = __int_as_float(se.y);
        float g  = embeds[((long long)col << 6) + lane];
        atomicAdd(&acc[(rloc << 6) + lane], v * g);
    }
    __syncthreads();

    int rowbase = b << 6;
    for (int i = threadIdx.x; i < BROWS * D_FEAT / 4; i += 256) {
        int r = rowbase + (i >> 4);              // 16 float4 per row
        if (r < NN) ((float4*)out)[(long long)r * 16 + (i & 15)] = acc4[i];
    }
}

// ---------------- fallback: baseline atomic scatter ----------------
__global__ void spmm_atomic_kernel(const int* __restrict__ rows, const int* __restrict__ cols,
                                   const float* __restrict__ vals, const float* __restrict__ embeds,
                                   float* __restrict__ out, int n_edges) {
    long long t = (long long)blockIdx.x * blockDim.x + threadIdx.x;
    int e = (int)(t >> 4);
    int f4 = ((int)t & 15) * 4;
    if (e >= n_edges) return;
    int r = rows[e], c = cols[e];
    float v = vals[e];
    const float4 emb = *reinterpret_cast<const float4*>(&embeds[(long long)c * D_FEAT + f4]);
    float* o = &out[(long long)r * D_FEAT + f4];
    atomicAdd(o + 0, v * emb.x);
    atomicAdd(o + 1, v * emb.y);
    atomicAdd(o + 2, v * emb.z);
    atomicAdd(o + 3, v * emb.w);
}

extern "C" void kernel_launch(void* const* d_in, const int* in_sizes, int n_in,
                              void* d_out, int out_size, void* d_ws, size_t ws_size,
                              hipStream_t stream) {
    const int*   rows   = (const int*)d_in[0];
    const int*   cols   = (const int*)d_in[1];
    const float* vals   = (const float*)d_in[2];
    const float* embeds = (const float*)d_in[3];
    float*       out    = (float*)d_out;
    int E = in_sizes[0];

    // Workspace: sedges (E int2), offsets (NBUCK+1), cursors (NBUCK)
    size_t need = (size_t)E * 8 + ((size_t)2 * NBUCK + 1) * 4;
    if (ws_size < need) {
        hipMemsetAsync(d_out, 0, (size_t)out_size * sizeof(float), stream);
        long long total = (long long)E * 16;
        int block = 256;
        spmm_atomic_kernel<<<(int)((total + block - 1) / block), block, 0, stream>>>(
            rows, cols, vals, embeds, out, E);
        return;
    }

    char* ws = (char*)d_ws;
    int2* sedges  = (int2*)ws;              ws += (size_t)E * 8;
    int*  offsets = (int*)ws;               ws += ((size_t)NBUCK + 1) * 4;
    int*  cursors = (int*)ws;

    // A: coarse histogram (counts accumulate in `cursors`)
    hipMemsetAsync(cursors, 0, (size_t)NBUCK * 4, stream);
    hist_bucket<<<256, 256, 0, stream>>>(rows, cursors, E);

    // B: scan counts -> offsets
    scan_small<<<1, 256, 0, stream>>>(cursors, offsets, E);

    // C: scatter edges into bucket regions
    hipMemsetAsync(cursors, 0, (size_t)NBUCK * 4, stream);
    cscatter_kernel<<<2048, 256, 0, stream>>>(rows, cols, vals, offsets, cursors, sedges, E);

    // D: bucket SpMM (covers every output row -> no out memset needed)
    bucket_spmm<<<NBUCK, 256, 0, stream>>>(offsets, sedges, embeds, out);
}

// Round 4
// 858.931 us; speedup vs baseline: 1.1767x; 1.1767x over previous
//
#include <hip/hip_runtime.h>

#define D_FEAT 64
#define NN 100000
#define BROWS 16                    // rows per bucket
#define NBUCK (NN / BROWS)          // 6250 exactly (100000 = 16*6250)

// ---------------- Phase A: coarse histogram (LDS-privatized, 25 KB) ----------------
__global__ void hist_bucket(const int* __restrict__ rows, int* __restrict__ counts, int E) {
    __shared__ int h[NBUCK];
    for (int i = threadIdx.x; i < NBUCK; i += blockDim.x) h[i] = 0;
    __syncthreads();
    int i = blockIdx.x * blockDim.x + threadIdx.x;
    int stride = gridDim.x * blockDim.x;
    for (; i < E; i += stride) atomicAdd(&h[rows[i] >> 4], 1);
    __syncthreads();
    for (int b = threadIdx.x; b < NBUCK; b += blockDim.x) {
        int v = h[b];
        if (v) atomicAdd(&counts[b], v);
    }
}

// ---------------- Phase B: exclusive scan over NBUCK counts (one block) ----------------
__global__ void scan_small(const int* __restrict__ counts, int* __restrict__ offsets, int E) {
    __shared__ int tsum[256];
    const int per = (NBUCK + 255) / 256;   // 25
    int t = threadIdx.x;
    int base = t * per;
    int s = 0;
    for (int k = 0; k < per; k++) {
        int idx = base + k;
        if (idx < NBUCK) s += counts[idx];
    }
    tsum[t] = s; __syncthreads();
    for (int off = 1; off < 256; off <<= 1) {
        int x = (t >= off) ? tsum[t - off] : 0;
        __syncthreads();
        tsum[t] += x;
        __syncthreads();
    }
    int excl = (t > 0) ? tsum[t - 1] : 0;
    for (int k = 0; k < per; k++) {
        int idx = base + k;
        if (idx < NBUCK) { offsets[idx] = excl; excl += counts[idx]; }
    }
    if (t == 0) offsets[NBUCK] = E;
}

// ---------------- Phase C: scatter edges into bucket regions ----------------
// Payload packs (col | rloc<<17, val): col < 2^17, rloc = row % 16 < 2^4.
__global__ void cscatter_kernel(const int* __restrict__ rows, const int* __restrict__ cols,
                                const float* __restrict__ vals,
                                const int* __restrict__ offsets, int* __restrict__ cursors,
                                int2* __restrict__ sedges, int E) {
    int i = blockIdx.x * blockDim.x + threadIdx.x;
    int stride = gridDim.x * blockDim.x;
    for (; i < E; i += stride) {
        int r = rows[i];
        int bkt = r >> 4;
        int pos = offsets[bkt] + atomicAdd(&cursors[bkt], 1);
        sedges[pos] = make_int2(cols[i] | ((r & 15) << 17), __float_as_int(vals[i]));
    }
}

// ---------------- Phase D: bucket SpMM, shfl-broadcast inner loop ----------------
// One block per 16-row bucket. LDS acc[16][64] = 4 KB. lane = feature.
// 4 waves each grab 64-edge chunks; lanes load edges coalesced, then a
// broadcast loop issues 8 independent gathers at a time (unroll 8).
__global__ void __launch_bounds__(256) bucket_spmm(const int* __restrict__ offsets,
                                                   const int2* __restrict__ sedges,
                                                   const float* __restrict__ embeds,
                                                   float* __restrict__ out) {
    __shared__ float acc[BROWS * D_FEAT];
    float4* acc4 = (float4*)acc;
    for (int i = threadIdx.x; i < BROWS * D_FEAT / 4; i += 256)
        acc4[i] = make_float4(0.f, 0.f, 0.f, 0.f);
    __syncthreads();

    int b = blockIdx.x;
    int s = offsets[b], e = offsets[b + 1];
    int lane = threadIdx.x & 63;
    int w = threadIdx.x >> 6;

    for (int base = s + (w << 6); base < e; base += 256) {
        int idx = base + lane;
        int px = 0; float pv = 0.f;
        if (idx < e) {
            int2 se = sedges[idx];
            px = se.x; pv = __int_as_float(se.y);
        }
        int m = min(64, e - base);
        if (m == 64) {
            #pragma unroll 8
            for (int j = 0; j < 64; j++) {
                int   pxj = __shfl(px, j);
                float vj  = __shfl(pv, j);
                float g = embeds[((pxj & 0x1FFFF) << 6) + lane];
                atomicAdd(&acc[(((pxj >> 17) & 15) << 6) + lane], vj * g);
            }
        } else {
            for (int j = 0; j < m; j++) {
                int   pxj = __shfl(px, j);
                float vj  = __shfl(pv, j);
                float g = embeds[((pxj & 0x1FFFF) << 6) + lane];
                atomicAdd(&acc[(((pxj >> 17) & 15) << 6) + lane], vj * g);
            }
        }
    }
    __syncthreads();

    // 16 rows x 16 float4 = 256 float4: exactly one per thread
    int rowbase = b * BROWS;
    int i = threadIdx.x;
    int r = rowbase + (i >> 4);
    ((float4*)out)[(size_t)r * 16 + (i & 15)] = acc4[i];
}

// ---------------- fallback: baseline atomic scatter ----------------
__global__ void spmm_atomic_kernel(const int* __restrict__ rows, const int* __restrict__ cols,
                                   const float* __restrict__ vals, const float* __restrict__ embeds,
                                   float* __restrict__ out, int n_edges) {
    long long t = (long long)blockIdx.x * blockDim.x + threadIdx.x;
    int e = (int)(t >> 4);
    int f4 = ((int)t & 15) * 4;
    if (e >= n_edges) return;
    int r = rows[e], c = cols[e];
    float v = vals[e];
    const float4 emb = *reinterpret_cast<const float4*>(&embeds[(long long)c * D_FEAT + f4]);
    float* o = &out[(long long)r * D_FEAT + f4];
    atomicAdd(o + 0, v * emb.x);
    atomicAdd(o + 1, v * emb.y);
    atomicAdd(o + 2, v * emb.z);
    atomicAdd(o + 3, v * emb.w);
}

extern "C" void kernel_launch(void* const* d_in, const int* in_sizes, int n_in,
                              void* d_out, int out_size, void* d_ws, size_t ws_size,
                              hipStream_t stream) {
    const int*   rows   = (const int*)d_in[0];
    const int*   cols   = (const int*)d_in[1];
    const float* vals   = (const float*)d_in[2];
    const float* embeds = (const float*)d_in[3];
    float*       out    = (float*)d_out;
    int E = in_sizes[0];

    // Workspace: sedges (E int2), offsets (NBUCK+1), cursors (NBUCK)
    size_t need = (size_t)E * 8 + ((size_t)2 * NBUCK + 1) * 4;
    if (ws_size < need) {
        hipMemsetAsync(d_out, 0, (size_t)out_size * sizeof(float), stream);
        long long total = (long long)E * 16;
        int block = 256;
        spmm_atomic_kernel<<<(int)((total + block - 1) / block), block, 0, stream>>>(
            rows, cols, vals, embeds, out, E);
        return;
    }

    char* ws = (char*)d_ws;
    int2* sedges  = (int2*)ws;              ws += (size_t)E * 8;
    int*  offsets = (int*)ws;               ws += ((size_t)NBUCK + 1) * 4;
    int*  cursors = (int*)ws;

    // A: coarse histogram (counts accumulate in `cursors`)
    hipMemsetAsync(cursors, 0, (size_t)NBUCK * 4, stream);
    hist_bucket<<<128, 256, 0, stream>>>(rows, cursors, E);

    // B: scan counts -> offsets
    scan_small<<<1, 256, 0, stream>>>(cursors, offsets, E);

    // C: scatter edges into bucket regions
    hipMemsetAsync(cursors, 0, (size_t)NBUCK * 4, stream);
    cscatter_kernel<<<2048, 256, 0, stream>>>(rows, cols, vals, offsets, cursors, sedges, E);

    // D: bucket SpMM (covers every output row -> no out memset needed)
    bucket_spmm<<<NBUCK, 256, 0, stream>>>(offsets, sedges, embeds, out);
}

// Round 5
// 294.117 us; speedup vs baseline: 3.4365x; 2.9204x over previous
//
#include <hip/hip_runtime.h>

#define D_FEAT 64
#define NN 100000
#define BROWS 4
#define NBUCK (NN / BROWS)          // 25000 exactly

// ---------------- Phase A: histogram (global atomics, counters L2-resident) ----------------
__global__ void hist_bucket(const int* __restrict__ rows, int* __restrict__ counts, int E) {
    int i = blockIdx.x * blockDim.x + threadIdx.x;
    int stride = gridDim.x * blockDim.x;
    for (; i < E; i += stride) atomicAdd(&counts[rows[i] >> 2], 1);
}

// ---------------- Phase B: exclusive scan over NBUCK counts (one block) ----------------
__global__ void scan_small(const int* __restrict__ counts, int* __restrict__ offsets, int E) {
    __shared__ int tsum[256];
    const int per = (NBUCK + 255) / 256;   // 98
    int t = threadIdx.x;
    int base = t * per;
    int s = 0;
    for (int k = 0; k < per; k++) {
        int idx = base + k;
        if (idx < NBUCK) s += counts[idx];
    }
    tsum[t] = s; __syncthreads();
    for (int off = 1; off < 256; off <<= 1) {
        int x = (t >= off) ? tsum[t - off] : 0;
        __syncthreads();
        tsum[t] += x;
        __syncthreads();
    }
    int excl = (t > 0) ? tsum[t - 1] : 0;
    for (int k = 0; k < per; k++) {
        int idx = base + k;
        if (idx < NBUCK) { offsets[idx] = excl; excl += counts[idx]; }
    }
    if (t == 0) offsets[NBUCK] = E;
}

// ---------------- Phase C: scatter edges into bucket regions ----------------
// Payload packs (col | rloc<<17, val): col < 2^17, rloc = row % 4 < 4.
__global__ void cscatter_kernel(const int* __restrict__ rows, const int* __restrict__ cols,
                                const float* __restrict__ vals,
                                const int* __restrict__ offsets, int* __restrict__ cursors,
                                int2* __restrict__ sedges, int E) {
    int i = blockIdx.x * blockDim.x + threadIdx.x;
    int stride = gridDim.x * blockDim.x;
    for (; i < E; i += stride) {
        int r = rows[i];
        int bkt = r >> 2;
        int pos = offsets[bkt] + atomicAdd(&cursors[bkt], 1);
        sedges[pos] = make_int2(cols[i] | ((r & 3) << 17), __float_as_int(vals[i]));
    }
}

// ---------------- Phase D: bucket SpMM — wave per 4-row bucket, register acc ----------------
// lane = feature. Stage 64 edges in wave-private LDS, read back with uniform
// ds_read_b64 (HW broadcast, no bpermute), accumulate into a0..a3 via
// branchless selects. Unroll 8 keeps 8 gathers in flight. No LDS atomics.
__global__ void __launch_bounds__(256) bucket_spmm(const int* __restrict__ offsets,
                                                   const int2* __restrict__ sedges,
                                                   const float* __restrict__ embeds,
                                                   float* __restrict__ out) {
    __shared__ int2 stage[4][64];
    int w    = threadIdx.x >> 6;
    int lane = threadIdx.x & 63;
    int bkt  = blockIdx.x * 4 + w;          // grid exact: 6250*4 = 25000 buckets

    int s = offsets[bkt], e = offsets[bkt + 1];
    float a0 = 0.f, a1 = 0.f, a2 = 0.f, a3 = 0.f;

    for (int base = s; base < e; base += 64) {
        int idx = base + lane;
        int2 se = (idx < e) ? sedges[idx] : make_int2(0, 0);   // tail: v=0 -> no-op
        stage[w][lane] = se;                                   // same-wave: compiler orders via lgkmcnt
        int m = e - base; if (m > 64) m = 64;
        int nsub = (m + 7) >> 3;
        for (int sb = 0; sb < nsub; sb++) {
            #pragma unroll
            for (int jj = 0; jj < 8; jj++) {
                int2  sv   = stage[w][sb * 8 + jj];            // uniform addr -> LDS broadcast
                float v    = __int_as_float(sv.y);
                int   col  = sv.x & 0x1FFFF;
                int   rloc = (sv.x >> 17) & 3;
                float g    = embeds[(col << 6) + lane];
                float x    = v * g;
                a0 += (rloc == 0) ? x : 0.f;
                a1 += (rloc == 1) ? x : 0.f;
                a2 += (rloc == 2) ? x : 0.f;
                a3 += (rloc == 3) ? x : 0.f;
            }
        }
    }

    size_t ob = (size_t)bkt * (BROWS * D_FEAT) + lane;
    out[ob]       = a0;
    out[ob + 64]  = a1;
    out[ob + 128] = a2;
    out[ob + 192] = a3;
}

// ---------------- fallback: baseline atomic scatter ----------------
__global__ void spmm_atomic_kernel(const int* __restrict__ rows, const int* __restrict__ cols,
                                   const float* __restrict__ vals, const float* __restrict__ embeds,
                                   float* __restrict__ out, int n_edges) {
    long long t = (long long)blockIdx.x * blockDim.x + threadIdx.x;
    int e = (int)(t >> 4);
    int f4 = ((int)t & 15) * 4;
    if (e >= n_edges) return;
    int r = rows[e], c = cols[e];
    float v = vals[e];
    const float4 emb = *reinterpret_cast<const float4*>(&embeds[(long long)c * D_FEAT + f4]);
    float* o = &out[(long long)r * D_FEAT + f4];
    atomicAdd(o + 0, v * emb.x);
    atomicAdd(o + 1, v * emb.y);
    atomicAdd(o + 2, v * emb.z);
    atomicAdd(o + 3, v * emb.w);
}

extern "C" void kernel_launch(void* const* d_in, const int* in_sizes, int n_in,
                              void* d_out, int out_size, void* d_ws, size_t ws_size,
                              hipStream_t stream) {
    const int*   rows   = (const int*)d_in[0];
    const int*   cols   = (const int*)d_in[1];
    const float* vals   = (const float*)d_in[2];
    const float* embeds = (const float*)d_in[3];
    float*       out    = (float*)d_out;
    int E = in_sizes[0];

    // Workspace: sedges (E int2), offsets (NBUCK+1), cursors (NBUCK)  ~= 13.0 MB
    size_t need = (size_t)E * 8 + ((size_t)2 * NBUCK + 1) * 4;
    if (ws_size < need) {
        hipMemsetAsync(d_out, 0, (size_t)out_size * sizeof(float), stream);
        long long total = (long long)E * 16;
        int block = 256;
        spmm_atomic_kernel<<<(int)((total + block - 1) / block), block, 0, stream>>>(
            rows, cols, vals, embeds, out, E);
        return;
    }

    char* ws = (char*)d_ws;
    int2* sedges  = (int2*)ws;              ws += (size_t)E * 8;
    int*  offsets = (int*)ws;               ws += ((size_t)NBUCK + 1) * 4;
    int*  cursors = (int*)ws;

    // A: histogram (counts accumulate in `cursors`)
    hipMemsetAsync(cursors, 0, (size_t)NBUCK * 4, stream);
    hist_bucket<<<1024, 256, 0, stream>>>(rows, cursors, E);

    // B: scan counts -> offsets
    scan_small<<<1, 256, 0, stream>>>(cursors, offsets, E);

    // C: scatter edges into bucket regions
    hipMemsetAsync(cursors, 0, (size_t)NBUCK * 4, stream);
    cscatter_kernel<<<2048, 256, 0, stream>>>(rows, cols, vals, offsets, cursors, sedges, E);

    // D: bucket SpMM (covers every output row -> no out memset needed)
    bucket_spmm<<<NBUCK / 4, 256, 0, stream>>>(offsets, sedges, embeds, out);
}

// Round 6
// 259.642 us; speedup vs baseline: 3.8928x; 1.1328x over previous
//
#include <hip/hip_runtime.h>

#define D_FEAT 64
#define NN 100000
#define BROWS 4
#define NBUCK (NN / BROWS)                  // 25000 fine buckets (4 rows each)
#define SBROWS 512
#define NSB ((NN + SBROWS - 1) / SBROWS)    // 196 super-buckets
#define FPS (SBROWS / BROWS)                // 128 fine buckets per SB
#define BATCH 8192                          // edges per coarse-split block

// ---------------- Phase A: fine histogram (global atomics, 100 KB L2-resident) ----------------
__global__ void hist_bucket(const int* __restrict__ rows, int* __restrict__ counts, int E) {
    int i = blockIdx.x * blockDim.x + threadIdx.x;
    int stride = gridDim.x * blockDim.x;
    for (; i < E; i += stride) atomicAdd(&counts[rows[i] >> 2], 1);
}

// ---------------- Phase B: exclusive scan over NBUCK counts (one block) ----------------
__global__ void scan_small(const int* __restrict__ counts, int* __restrict__ offsets, int E) {
    __shared__ int tsum[256];
    const int per = (NBUCK + 255) / 256;
    int t = threadIdx.x;
    int base = t * per;
    int s = 0;
    for (int k = 0; k < per; k++) {
        int idx = base + k;
        if (idx < NBUCK) s += counts[idx];
    }
    tsum[t] = s; __syncthreads();
    for (int off = 1; off < 256; off <<= 1) {
        int x = (t >= off) ? tsum[t - off] : 0;
        __syncthreads();
        tsum[t] += x;
        __syncthreads();
    }
    int excl = (t > 0) ? tsum[t - 1] : 0;
    for (int k = 0; k < per; k++) {
        int idx = base + k;
        if (idx < NBUCK) { offsets[idx] = excl; excl += counts[idx]; }
    }
    if (t == 0) offsets[NBUCK] = E;
}

// ---------------- init: coarse cursors start at each SB's global base ----------------
__global__ void init_ccursors(const int* __restrict__ offsets, int* __restrict__ ccursors) {
    int t = threadIdx.x;
    if (t < NSB) {
        int idx = t * FPS; if (idx > NBUCK) idx = NBUCK;
        ccursors[t] = offsets[idx];
    }
}

// ---------------- Phase C1: coarse multisplit with LDS binning ----------------
// Each block: hist 8192 edges over 196 SBs -> LDS scan -> reserve chunk per SB
// (one global atomic per bin) -> bin-sort batch into LDS -> flush bins with
// contiguous coalesced writes (single wave per line -> write amp ~1).
__global__ void __launch_bounds__(512) coarse_split(const int* __restrict__ rows,
                                                    const int* __restrict__ cols,
                                                    const float* __restrict__ vals,
                                                    int* __restrict__ ccursors,
                                                    int2* __restrict__ tmp, int E) {
    __shared__ int2 pay[BATCH];               // 64 KB
    __shared__ int hist[NSB], scanv[NSB], lcur[NSB], gbase[NSB];
    __shared__ int tsum[256];

    int b0 = blockIdx.x * BATCH;
    int n = E - b0; if (n > BATCH) n = BATCH;
    int t = threadIdx.x;

    for (int i = t; i < NSB; i += 512) hist[i] = 0;
    __syncthreads();

    // pass 1: histogram by super-bucket
    for (int k = t; k < n; k += 512)
        atomicAdd(&hist[rows[b0 + k] >> 9], 1);
    __syncthreads();

    // exclusive scan over NSB (<=256) via Hillis-Steele on lanes 0..255
    if (t < 256) tsum[t] = (t < NSB) ? hist[t] : 0;
    __syncthreads();
    for (int off = 1; off < 256; off <<= 1) {
        int x = 0;
        if (t < 256 && t >= off) x = tsum[t - off];
        __syncthreads();
        if (t < 256) tsum[t] += x;
        __syncthreads();
    }
    if (t < NSB) {
        int excl = (t > 0) ? tsum[t - 1] : 0;
        scanv[t] = excl;
        lcur[t]  = excl;
        gbase[t] = atomicAdd(&ccursors[t], hist[t]);   // absolute reserved base
    }
    __syncthreads();

    // pass 2: place edges into LDS bins (payload: col | (r&511)<<17, val)
    for (int k = t; k < n; k += 512) {
        int r  = rows[b0 + k];
        int sb = r >> 9;
        int idx = atomicAdd(&lcur[sb], 1);
        pay[idx] = make_int2(cols[b0 + k] | ((r & 511) << 17), __float_as_int(vals[b0 + k]));
    }
    __syncthreads();

    // flush: contiguous per-bin copies (coalesced, wide)
    for (int s = 0; s < NSB; ++s) {
        int cnt = hist[s];
        int sv = scanv[s], gb = gbase[s];
        for (int j = t; j < cnt; j += 512) tmp[gb + j] = pay[sv + j];
    }
}

// ---------------- Phase C2: per-SB fine split (single block = single XCD writes) ----------------
__global__ void __launch_bounds__(512) fine_split(const int2* __restrict__ tmp,
                                                  const int* __restrict__ offsets,
                                                  int2* __restrict__ sedges) {
    __shared__ int lcur[FPS];
    __shared__ int lbase[FPS];
    int sb = blockIdx.x;
    int t = threadIdx.x;
    int f0 = sb * FPS;
    if (t < FPS) {
        int idx = f0 + t;
        lcur[t]  = 0;
        lbase[t] = (idx < NBUCK) ? offsets[idx] : 0;
    }
    __syncthreads();
    int s_idx = f0;        if (s_idx > NBUCK) s_idx = NBUCK;
    int e_idx = f0 + FPS;  if (e_idx > NBUCK) e_idx = NBUCK;
    int cstart = offsets[s_idx];
    int cend   = offsets[e_idx];
    for (int i = cstart + t; i < cend; i += 512) {
        int2 p = tmp[i];
        int fl = (p.x >> 19) & (FPS - 1);               // (r&511)>>2
        int pos = lbase[fl] + atomicAdd(&lcur[fl], 1);
        sedges[pos] = make_int2(p.x & 0x7FFFF, p.y);    // keep col + (r&3)<<17
    }
}

// ---------------- Phase C (fallback tier): single-pass scatter ----------------
__global__ void cscatter_kernel(const int* __restrict__ rows, const int* __restrict__ cols,
                                const float* __restrict__ vals,
                                const int* __restrict__ offsets, int* __restrict__ cursors,
                                int2* __restrict__ sedges, int E) {
    int i = blockIdx.x * blockDim.x + threadIdx.x;
    int stride = gridDim.x * blockDim.x;
    for (; i < E; i += stride) {
        int r = rows[i];
        int bkt = r >> 2;
        int pos = offsets[bkt] + atomicAdd(&cursors[bkt], 1);
        sedges[pos] = make_int2(cols[i] | ((r & 3) << 17), __float_as_int(vals[i]));
    }
}

// ---------------- Phase D: bucket SpMM — wave per 4-row bucket, register acc ----------------
__global__ void __launch_bounds__(256) bucket_spmm(const int* __restrict__ offsets,
                                                   const int2* __restrict__ sedges,
                                                   const float* __restrict__ embeds,
                                                   float* __restrict__ out) {
    __shared__ int2 stage[4][64];
    int w    = threadIdx.x >> 6;
    int lane = threadIdx.x & 63;
    int bkt  = blockIdx.x * 4 + w;

    int s = offsets[bkt], e = offsets[bkt + 1];
    float a0 = 0.f, a1 = 0.f, a2 = 0.f, a3 = 0.f;

    for (int base = s; base < e; base += 64) {
        int idx = base + lane;
        int2 se = (idx < e) ? sedges[idx] : make_int2(0, 0);
        stage[w][lane] = se;
        int m = e - base; if (m > 64) m = 64;
        int nsub = (m + 7) >> 3;
        for (int sb = 0; sb < nsub; sb++) {
            #pragma unroll
            for (int jj = 0; jj < 8; jj++) {
                int2  sv   = stage[w][sb * 8 + jj];
                float v    = __int_as_float(sv.y);
                int   col  = sv.x & 0x1FFFF;
                int   rloc = (sv.x >> 17) & 3;
                float g    = embeds[(col << 6) + lane];
                float x    = v * g;
                a0 += (rloc == 0) ? x : 0.f;
                a1 += (rloc == 1) ? x : 0.f;
                a2 += (rloc == 2) ? x : 0.f;
                a3 += (rloc == 3) ? x : 0.f;
            }
        }
    }

    size_t ob = (size_t)bkt * (BROWS * D_FEAT) + lane;
    out[ob]       = a0;
    out[ob + 64]  = a1;
    out[ob + 128] = a2;
    out[ob + 192] = a3;
}

// ---------------- fallback: baseline atomic scatter ----------------
__global__ void spmm_atomic_kernel(const int* __restrict__ rows, const int* __restrict__ cols,
                                   const float* __restrict__ vals, const float* __restrict__ embeds,
                                   float* __restrict__ out, int n_edges) {
    long long t = (long long)blockIdx.x * blockDim.x + threadIdx.x;
    int e = (int)(t >> 4);
    int f4 = ((int)t & 15) * 4;
    if (e >= n_edges) return;
    int r = rows[e], c = cols[e];
    float v = vals[e];
    const float4 emb = *reinterpret_cast<const float4*>(&embeds[(long long)c * D_FEAT + f4]);
    float* o = &out[(long long)r * D_FEAT + f4];
    atomicAdd(o + 0, v * emb.x);
    atomicAdd(o + 1, v * emb.y);
    atomicAdd(o + 2, v * emb.z);
    atomicAdd(o + 3, v * emb.w);
}

extern "C" void kernel_launch(void* const* d_in, const int* in_sizes, int n_in,
                              void* d_out, int out_size, void* d_ws, size_t ws_size,
                              hipStream_t stream) {
    const int*   rows   = (const int*)d_in[0];
    const int*   cols   = (const int*)d_in[1];
    const float* vals   = (const float*)d_in[2];
    const float* embeds = (const float*)d_in[3];
    float*       out    = (float*)d_out;
    int E = in_sizes[0];

    // Full path workspace: tmp (E int2) + sedges (E int2) + offsets + fcounts + ccursors
    size_t need2 = (size_t)E * 16 + ((size_t)2 * NBUCK + 1 + NSB) * 4;   // ~25.8 MB
    size_t need1 = (size_t)E * 8  + ((size_t)2 * NBUCK + 1) * 4;         // ~13 MB

    if (ws_size >= need2) {
        char* ws = (char*)d_ws;
        int2* tmp     = (int2*)ws;          ws += (size_t)E * 8;
        int2* sedges  = (int2*)ws;          ws += (size_t)E * 8;
        int*  offsets = (int*)ws;           ws += ((size_t)NBUCK + 1) * 4;
        int*  fcounts = (int*)ws;           ws += (size_t)NBUCK * 4;
        int*  ccursors= (int*)ws;

        hipMemsetAsync(fcounts, 0, (size_t)NBUCK * 4, stream);
        hist_bucket<<<1024, 256, 0, stream>>>(rows, fcounts, E);
        scan_small<<<1, 256, 0, stream>>>(fcounts, offsets, E);
        init_ccursors<<<1, 256, 0, stream>>>(offsets, ccursors);

        int nb1 = (E + BATCH - 1) / BATCH;
        coarse_split<<<nb1, 512, 0, stream>>>(rows, cols, vals, ccursors, tmp, E);
        fine_split<<<NSB, 512, 0, stream>>>(tmp, offsets, sedges);

        bucket_spmm<<<NBUCK / 4, 256, 0, stream>>>(offsets, sedges, embeds, out);
    } else if (ws_size >= need1) {
        char* ws = (char*)d_ws;
        int2* sedges  = (int2*)ws;          ws += (size_t)E * 8;
        int*  offsets = (int*)ws;           ws += ((size_t)NBUCK + 1) * 4;
        int*  cursors = (int*)ws;

        hipMemsetAsync(cursors, 0, (size_t)NBUCK * 4, stream);
        hist_bucket<<<1024, 256, 0, stream>>>(rows, cursors, E);
        scan_small<<<1, 256, 0, stream>>>(cursors, offsets, E);
        hipMemsetAsync(cursors, 0, (size_t)NBUCK * 4, stream);
        cscatter_kernel<<<2048, 256, 0, stream>>>(rows, cols, vals, offsets, cursors, sedges, E);
        bucket_spmm<<<NBUCK / 4, 256, 0, stream>>>(offsets, sedges, embeds, out);
    } else {
        hipMemsetAsync(d_out, 0, (size_t)out_size * sizeof(float), stream);
        long long total = (long long)E * 16;
        int block = 256;
        spmm_atomic_kernel<<<(int)((total + block - 1) / block), block, 0, stream>>>(
            rows, cols, vals, embeds, out, E);
    }
}

// Round 7
// 127.037 us; speedup vs baseline: 7.9563x; 2.0438x over previous
//
#include <hip/hip_runtime.h>

#define D_FEAT 64
#define NN 100000
#define BROWS 4
#define NBUCK (NN / BROWS)                  // 25000 fine buckets (4 rows each)
#define SBROWS 512
#define NSB ((NN + SBROWS - 1) / SBROWS)    // 196 super-buckets
#define FPS (SBROWS / BROWS)                // 128 fine buckets per SB
#define BATCH 8192                          // edges per coarse-split block

// ---------------- Phase A: coarse histogram (LDS-privatized, 196 bins) ----------------
__global__ void coarse_hist(const int* __restrict__ rows, int* __restrict__ ccounts, int E) {
    __shared__ int h[NSB];
    for (int i = threadIdx.x; i < NSB; i += blockDim.x) h[i] = 0;
    __syncthreads();
    int i = blockIdx.x * blockDim.x + threadIdx.x;
    int stride = gridDim.x * blockDim.x;
    for (; i < E; i += stride) atomicAdd(&h[rows[i] >> 9], 1);
    __syncthreads();
    for (int b = threadIdx.x; b < NSB; b += blockDim.x) {
        int v = h[b];
        if (v) atomicAdd(&ccounts[b], v);
    }
}

// ---------------- Phase B: scan 196 coarse counts -> coarse_off + ccursors ----------------
__global__ void scan_coarse(const int* __restrict__ ccounts, int* __restrict__ coarse_off,
                            int* __restrict__ ccursors, int E) {
    __shared__ int tsum[256];
    int t = threadIdx.x;
    tsum[t] = (t < NSB) ? ccounts[t] : 0;
    __syncthreads();
    for (int off = 1; off < 256; off <<= 1) {
        int x = (t >= off) ? tsum[t - off] : 0;
        __syncthreads();
        tsum[t] += x;
        __syncthreads();
    }
    if (t < NSB) {
        int excl = (t > 0) ? tsum[t - 1] : 0;
        coarse_off[t] = excl;
        ccursors[t]   = excl;
    }
    if (t == 0) coarse_off[NSB] = E;
}

// ---------------- Phase C1: coarse multisplit with LDS binning ----------------
// Payload: col(17b) | (r&511)<<17  (26 bits).
__global__ void __launch_bounds__(512) coarse_split(const int* __restrict__ rows,
                                                    const int* __restrict__ cols,
                                                    const float* __restrict__ vals,
                                                    int* __restrict__ ccursors,
                                                    int2* __restrict__ tmp, int E) {
    __shared__ int2 pay[BATCH];               // 64 KB
    __shared__ int hist[NSB], scanv[NSB], lcur[NSB], gbase[NSB];
    __shared__ int tsum[256];

    int b0 = blockIdx.x * BATCH;
    int n = E - b0; if (n > BATCH) n = BATCH;
    int t = threadIdx.x;

    for (int i = t; i < NSB; i += 512) hist[i] = 0;
    __syncthreads();

    // pass 1: histogram by super-bucket
    for (int k = t; k < n; k += 512)
        atomicAdd(&hist[rows[b0 + k] >> 9], 1);
    __syncthreads();

    // exclusive scan over NSB (<=256)
    if (t < 256) tsum[t] = (t < NSB) ? hist[t] : 0;
    __syncthreads();
    for (int off = 1; off < 256; off <<= 1) {
        int x = 0;
        if (t < 256 && t >= off) x = tsum[t - off];
        __syncthreads();
        if (t < 256) tsum[t] += x;
        __syncthreads();
    }
    if (t < NSB) {
        int excl = (t > 0) ? tsum[t - 1] : 0;
        scanv[t] = excl;
        lcur[t]  = excl;
        gbase[t] = atomicAdd(&ccursors[t], hist[t]);   // absolute reserved base
    }
    __syncthreads();

    // pass 2: place edges into LDS bins
    for (int k = t; k < n; k += 512) {
        int r  = rows[b0 + k];
        int sb = r >> 9;
        int idx = atomicAdd(&lcur[sb], 1);
        pay[idx] = make_int2(cols[b0 + k] | ((r & 511) << 17), __float_as_int(vals[b0 + k]));
    }
    __syncthreads();

    // flush: wave-per-bin contiguous copies
    int wv = t >> 6, ln = t & 63;
    for (int s = wv; s < NSB; s += 8) {
        int cnt = hist[s];
        int sv = scanv[s], gb = gbase[s];
        for (int j = ln; j < cnt; j += 64) tmp[gb + j] = pay[sv + j];
    }
}

// ---------------- Phase C2: per-SB fine split + local hist/scan -> fine offsets ----------------
__global__ void __launch_bounds__(1024) fine_split(const int2* __restrict__ tmp,
                                                   const int* __restrict__ coarse_off,
                                                   int* __restrict__ offsets,
                                                   int2* __restrict__ sedges, int E) {
    __shared__ int lhist[FPS], lbase[FPS], lcur[FPS], tt[FPS];
    int sb = blockIdx.x;
    int t = threadIdx.x;
    int f0 = sb * FPS;
    int nf = NBUCK - f0; if (nf > FPS) nf = FPS;
    int cstart = coarse_off[sb], cend = coarse_off[sb + 1];

    if (t < FPS) lhist[t] = 0;
    __syncthreads();

    // pass 1: fine histogram of this SB's window (L2-hot)
    for (int i = cstart + t; i < cend; i += 1024)
        atomicAdd(&lhist[(tmp[i].x >> 19) & (FPS - 1)], 1);
    __syncthreads();

    // exclusive scan of 128 bins
    if (t < FPS) tt[t] = lhist[t];
    __syncthreads();
    for (int off = 1; off < FPS; off <<= 1) {
        int x = 0;
        if (t < FPS && t >= off) x = tt[t - off];
        __syncthreads();
        if (t < FPS) tt[t] += x;
        __syncthreads();
    }
    if (t < FPS) {
        int excl = (t > 0) ? tt[t - 1] : 0;
        lbase[t] = cstart + excl;
        lcur[t]  = 0;
        if (t < nf) offsets[f0 + t] = cstart + excl;   // global fine offsets
    }
    if (sb == NSB - 1 && t == 0) offsets[NBUCK] = E;
    __syncthreads();

    // pass 2: scatter within the SB window (single block = single XCD writes)
    for (int i = cstart + t; i < cend; i += 1024) {
        int2 p = tmp[i];
        int fl = (p.x >> 19) & (FPS - 1);
        int pos = lbase[fl] + atomicAdd(&lcur[fl], 1);
        sedges[pos] = make_int2(p.x & 0x7FFFF, p.y);   // col + (r&3)<<17
    }
}

// ---------------- tier-1 fallback kernels ----------------
__global__ void hist_bucket(const int* __restrict__ rows, int* __restrict__ counts, int E) {
    int i = blockIdx.x * blockDim.x + threadIdx.x;
    int stride = gridDim.x * blockDim.x;
    for (; i < E; i += stride) atomicAdd(&counts[rows[i] >> 2], 1);
}

__global__ void scan_small(const int* __restrict__ counts, int* __restrict__ offsets, int E) {
    __shared__ int tsum[256];
    const int per = (NBUCK + 255) / 256;
    int t = threadIdx.x;
    int base = t * per;
    int s = 0;
    for (int k = 0; k < per; k++) {
        int idx = base + k;
        if (idx < NBUCK) s += counts[idx];
    }
    tsum[t] = s; __syncthreads();
    for (int off = 1; off < 256; off <<= 1) {
        int x = (t >= off) ? tsum[t - off] : 0;
        __syncthreads();
        tsum[t] += x;
        __syncthreads();
    }
    int excl = (t > 0) ? tsum[t - 1] : 0;
    for (int k = 0; k < per; k++) {
        int idx = base + k;
        if (idx < NBUCK) { offsets[idx] = excl; excl += counts[idx]; }
    }
    if (t == 0) offsets[NBUCK] = E;
}

__global__ void cscatter_kernel(const int* __restrict__ rows, const int* __restrict__ cols,
                                const float* __restrict__ vals,
                                const int* __restrict__ offsets, int* __restrict__ cursors,
                                int2* __restrict__ sedges, int E) {
    int i = blockIdx.x * blockDim.x + threadIdx.x;
    int stride = gridDim.x * blockDim.x;
    for (; i < E; i += stride) {
        int r = rows[i];
        int bkt = r >> 2;
        int pos = offsets[bkt] + atomicAdd(&cursors[bkt], 1);
        sedges[pos] = make_int2(cols[i] | ((r & 3) << 17), __float_as_int(vals[i]));
    }
}

// ---------------- Phase D: bucket SpMM — wave per 4-row bucket, register acc ----------------
__global__ void __launch_bounds__(256) bucket_spmm(const int* __restrict__ offsets,
                                                   const int2* __restrict__ sedges,
                                                   const float* __restrict__ embeds,
                                                   float* __restrict__ out) {
    __shared__ int2 stage[4][64];
    int w    = threadIdx.x >> 6;
    int lane = threadIdx.x & 63;
    int bkt  = blockIdx.x * 4 + w;

    int s = offsets[bkt], e = offsets[bkt + 1];
    float a0 = 0.f, a1 = 0.f, a2 = 0.f, a3 = 0.f;

    for (int base = s; base < e; base += 64) {
        int idx = base + lane;
        int2 se = (idx < e) ? sedges[idx] : make_int2(0, 0);
        stage[w][lane] = se;
        int m = e - base; if (m > 64) m = 64;
        int nsub = (m + 7) >> 3;
        for (int sub = 0; sub < nsub; sub++) {
            #pragma unroll
            for (int jj = 0; jj < 8; jj++) {
                int2  sv   = stage[w][sub * 8 + jj];
                float v    = __int_as_float(sv.y);
                int   col  = sv.x & 0x1FFFF;
                int   rloc = (sv.x >> 17) & 3;
                float g    = embeds[(col << 6) + lane];
                float x    = v * g;
                a0 += (rloc == 0) ? x : 0.f;
                a1 += (rloc == 1) ? x : 0.f;
                a2 += (rloc == 2) ? x : 0.f;
                a3 += (rloc == 3) ? x : 0.f;
            }
        }
    }

    size_t ob = (size_t)bkt * (BROWS * D_FEAT) + lane;
    out[ob]       = a0;
    out[ob + 64]  = a1;
    out[ob + 128] = a2;
    out[ob + 192] = a3;
}

// ---------------- tier-0 fallback: baseline atomic scatter ----------------
__global__ void spmm_atomic_kernel(const int* __restrict__ rows, const int* __restrict__ cols,
                                   const float* __restrict__ vals, const float* __restrict__ embeds,
                                   float* __restrict__ out, int n_edges) {
    long long t = (long long)blockIdx.x * blockDim.x + threadIdx.x;
    int e = (int)(t >> 4);
    int f4 = ((int)t & 15) * 4;
    if (e >= n_edges) return;
    int r = rows[e], c = cols[e];
    float v = vals[e];
    const float4 emb = *reinterpret_cast<const float4*>(&embeds[(long long)c * D_FEAT + f4]);
    float* o = &out[(long long)r * D_FEAT + f4];
    atomicAdd(o + 0, v * emb.x);
    atomicAdd(o + 1, v * emb.y);
    atomicAdd(o + 2, v * emb.z);
    atomicAdd(o + 3, v * emb.w);
}

extern "C" void kernel_launch(void* const* d_in, const int* in_sizes, int n_in,
                              void* d_out, int out_size, void* d_ws, size_t ws_size,
                              hipStream_t stream) {
    const int*   rows   = (const int*)d_in[0];
    const int*   cols   = (const int*)d_in[1];
    const float* vals   = (const float*)d_in[2];
    const float* embeds = (const float*)d_in[3];
    float*       out    = (float*)d_out;
    int E = in_sizes[0];

    // tier-2: tmp + sedges + offsets + ccounts + coarse_off + ccursors
    size_t need2 = (size_t)E * 16 + ((size_t)NBUCK + 1 + 3 * NSB + 1) * 4;
    size_t need1 = (size_t)E * 8  + ((size_t)2 * NBUCK + 1) * 4;

    if (ws_size >= need2) {
        char* ws = (char*)d_ws;
        int2* tmp       = (int2*)ws;        ws += (size_t)E * 8;
        int2* sedges    = (int2*)ws;        ws += (size_t)E * 8;
        int*  offsets   = (int*)ws;         ws += ((size_t)NBUCK + 1) * 4;
        int*  ccounts   = (int*)ws;         ws += (size_t)NSB * 4;
        int*  coarse_off= (int*)ws;         ws += ((size_t)NSB + 1) * 4;
        int*  ccursors  = (int*)ws;

        hipMemsetAsync(ccounts, 0, (size_t)NSB * 4, stream);
        coarse_hist<<<256, 256, 0, stream>>>(rows, ccounts, E);
        scan_coarse<<<1, 256, 0, stream>>>(ccounts, coarse_off, ccursors, E);

        int nb1 = (E + BATCH - 1) / BATCH;
        coarse_split<<<nb1, 512, 0, stream>>>(rows, cols, vals, ccursors, tmp, E);
        fine_split<<<NSB, 1024, 0, stream>>>(tmp, coarse_off, offsets, sedges, E);

        bucket_spmm<<<NBUCK / 4, 256, 0, stream>>>(offsets, sedges, embeds, out);
    } else if (ws_size >= need1) {
        char* ws = (char*)d_ws;
        int2* sedges  = (int2*)ws;          ws += (size_t)E * 8;
        int*  offsets = (int*)ws;           ws += ((size_t)NBUCK + 1) * 4;
        int*  cursors = (int*)ws;

        hipMemsetAsync(cursors, 0, (size_t)NBUCK * 4, stream);
        hist_bucket<<<1024, 256, 0, stream>>>(rows, cursors, E);
        scan_small<<<1, 256, 0, stream>>>(cursors, offsets, E);
        hipMemsetAsync(cursors, 0, (size_t)NBUCK * 4, stream);
        cscatter_kernel<<<2048, 256, 0, stream>>>(rows, cols, vals, offsets, cursors, sedges, E);
        bucket_spmm<<<NBUCK / 4, 256, 0, stream>>>(offsets, sedges, embeds, out);
    } else {
        hipMemsetAsync(d_out, 0, (size_t)out_size * sizeof(float), stream);
        long long total = (long long)E * 16;
        int block = 256;
        spmm_atomic_kernel<<<(int)((total + block - 1) / block), block, 0, stream>>>(
            rows, cols, vals, embeds, out, E);
    }
}